// Round 5
// baseline (291.238 us; speedup 1.0000x reference)
//
#include <hip/hip_runtime.h>

typedef short bf16x8 __attribute__((ext_vector_type(8)));
typedef float f32x4 __attribute__((ext_vector_type(4)));
typedef unsigned int u32;

#define NT 32
#define NB 4096
#define ND 32
#define NW 64

// Dopri5 tableau
#define A31 ((float)(3.0/40.0))
#define A32 ((float)(9.0/40.0))
#define A41 ((float)(44.0/45.0))
#define A42 ((float)(-56.0/15.0))
#define A43 ((float)(32.0/9.0))
#define A51 ((float)(19372.0/6561.0))
#define A52 ((float)(-25360.0/2187.0))
#define A53 ((float)(64448.0/6561.0))
#define A54 ((float)(-212.0/729.0))
#define A61 ((float)(9017.0/3168.0))
#define A62 ((float)(-355.0/33.0))
#define A63 ((float)(46732.0/5247.0))
#define A64 ((float)(49.0/176.0))
#define A65 ((float)(-5103.0/18656.0))
#define BB1 ((float)(35.0/384.0))
#define BB3 ((float)(500.0/1113.0))
#define BB4 ((float)(125.0/192.0))
#define BB5 ((float)(-2187.0/6784.0))
#define BB6 ((float)(11.0/84.0))

// Single-instruction RNE pack: D.lo = bf16(a), D.hi = bf16(b)
__device__ __forceinline__ u32 pk(float a, float b) {
    u32 r;
    asm("v_cvt_pk_bf16_f32 %0, %1, %2" : "=v"(r) : "v"(a), "v"(b));
    return r;
}
__device__ __forceinline__ float sp(float x) {      // softplus, numerically stable
    return fmaxf(x, 0.0f) + __logf(1.0f + __expf(-fabsf(x)));
}
__device__ __forceinline__ bf16x8 mk_afrag(const float* p) {
    union { u32 u[4]; bf16x8 v; } r;
    r.u[0] = pk(p[0], p[1]); r.u[1] = pk(p[2], p[3]);
    r.u[2] = pk(p[4], p[5]); r.u[3] = pk(p[6], p[7]);
    return r.v;
}

// Structure (per 16-row group, 4 waves):
//   - RK state y + k1..k6 held REPLICATED on all 4 waves in D-layout
//     (lane 16q+n owns y[n][mt*16+4q+j], mt=0,1; j=0..3).
//   - L1/L2: wave w owns hidden m-tile w; h1/h2 exchanged via shared LDS
//     (XOR-swizzled 128B rows) -> barriers B1, B2 only.
//   - L3 + RK combine: redundant on ALL waves (h2 is in LDS after B2);
//     next y B-frag built via private per-wave LDS bounce (intra-wave
//     lgkmcnt sync only, NO barrier). 2 barriers/eval total.

__global__ __launch_bounds__(256, 1)
void node_kernel(const float* __restrict__ ts, const float* __restrict__ y0,
                 const float* __restrict__ W1, const float* __restrict__ b1,
                 const float* __restrict__ W2, const float* __restrict__ b2,
                 const float* __restrict__ W3, const float* __restrict__ b3,
                 float* __restrict__ out)
{
    __shared__ __align__(16) u32 h1ds[16 * 32];
    __shared__ __align__(16) u32 h2ds[16 * 32];
    __shared__ __align__(16) u32 ybuf[4][16 * 16];   // per-wave private bounce
    __shared__ float hsl[NT];

    const int tid  = threadIdx.x;
    const int w    = tid >> 6;          // wave 0..3
    const int lane = tid & 63;
    const int n    = lane & 15;         // batch col
    const int q    = lane >> 4;         // MFMA quad (also B-frag k-chunk)
    const int swz  = (n & 7) << 2;      // XOR for 32-u32 rows (h1/h2)
    const int ysw  = (n & 3) << 2;      // XOR for 16-u32 rows (ybuf)
    const int row0 = blockIdx.x * 16;

    if (tid < NT - 1) hsl[tid] = (ts[tid + 1] - ts[tid]) * 0.5f;  // K=2

    // ---- weights ----
    bf16x8 a1   = mk_afrag(W1 + (w * 16 + n) * ND + q * 8);
    bf16x8 a2lo = mk_afrag(W2 + (w * 16 + n) * NW + q * 8);
    bf16x8 a2hi = mk_afrag(W2 + (w * 16 + n) * NW + 32 + q * 8);
    bf16x8 a3[2][2];
    #pragma unroll
    for (int mt = 0; mt < 2; ++mt) {
        a3[mt][0] = mk_afrag(W3 + (mt * 16 + n) * NW + q * 8);
        a3[mt][1] = mk_afrag(W3 + (mt * 16 + n) * NW + 32 + q * 8);
    }
    f32x4 bs1 = *(const f32x4*)(b1 + w * 16 + q * 4);
    f32x4 bs2 = *(const f32x4*)(b2 + w * 16 + q * 4);
    f32x4 bs3[2];
    bs3[0] = *(const f32x4*)(b3 + q * 4);
    bs3[1] = *(const f32x4*)(b3 + 16 + q * 4);
    const f32x4 zed = {0.0f, 0.0f, 0.0f, 0.0f};

    // ---- RK state, D-layout, replicated on all waves ----
    f32x4 yD0 = *(const f32x4*)(y0 + (size_t)(row0 + n) * ND + 4 * q);
    f32x4 yD1 = *(const f32x4*)(y0 + (size_t)(row0 + n) * ND + 16 + 4 * q);
    if (w == 0) {
        *(f32x4*)(out + (size_t)(row0 + n) * ND + 4 * q) = yD0;       // ys[0]
        *(f32x4*)(out + (size_t)(row0 + n) * ND + 16 + 4 * q) = yD1;
    }
    __syncthreads();    // hsl visible before loop

    u32* myy = &ybuf[w][0];

    // D-layout stage-y -> bf16 B-frag via private LDS bounce (no barrier)
    auto bounce = [&](f32x4 s0, f32x4 s1) -> bf16x8 {
        uint2 p0, p1;
        p0.x = pk(s0[0], s0[1]); p0.y = pk(s0[2], s0[3]);
        p1.x = pk(s1[0], s1[1]); p1.y = pk(s1[2], s1[3]);
        *(uint2*)&myy[n * 16 + ((2 * q) ^ ysw)]     = p0;   // mt=0: dims 4q..4q+3
        *(uint2*)&myy[n * 16 + ((8 + 2 * q) ^ ysw)] = p1;   // mt=1: dims 16+4q..
        return *(const bf16x8*)&myy[n * 16 + ((4 * q) ^ ysw)];  // y[n][8q..8q+7]
    };

    auto evalf = [&](bf16x8 by, f32x4& k0, f32x4& k1) {
        // L1: wave's hidden m-tile
        f32x4 u = __builtin_amdgcn_mfma_f32_16x16x32_bf16(a1, by, bs1, 0, 0, 0);
        uint2 p;
        p.x = pk(sp(u[0]), sp(u[1])); p.y = pk(sp(u[2]), sp(u[3]));
        *(uint2*)&h1ds[n * 32 + ((w * 8 + 2 * q) ^ swz)] = p;
        __syncthreads();                                     // B1: h1 ready
        bf16x8 bh0 = *(const bf16x8*)&h1ds[n * 32 + ((4 * q) ^ swz)];
        bf16x8 bh1 = *(const bf16x8*)&h1ds[n * 32 + ((16 + 4 * q) ^ swz)];
        f32x4 va = __builtin_amdgcn_mfma_f32_16x16x32_bf16(a2lo, bh0, bs2, 0, 0, 0);
        f32x4 vb = __builtin_amdgcn_mfma_f32_16x16x32_bf16(a2hi, bh1, zed, 0, 0, 0);
        f32x4 v = va + vb;
        p.x = pk(sp(v[0]), sp(v[1])); p.y = pk(sp(v[2]), sp(v[3]));
        *(uint2*)&h2ds[n * 32 + ((w * 8 + 2 * q) ^ swz)] = p;
        __syncthreads();                                     // B2: h2 ready
        bf16x8 c0 = *(const bf16x8*)&h2ds[n * 32 + ((4 * q) ^ swz)];
        bf16x8 c1 = *(const bf16x8*)&h2ds[n * 32 + ((16 + 4 * q) ^ swz)];
        // L3 redundant on all waves; 4 independent MFMAs (C-chains broken)
        f32x4 ka = __builtin_amdgcn_mfma_f32_16x16x32_bf16(a3[0][0], c0, bs3[0], 0, 0, 0);
        f32x4 kb = __builtin_amdgcn_mfma_f32_16x16x32_bf16(a3[0][1], c1, zed, 0, 0, 0);
        f32x4 kc = __builtin_amdgcn_mfma_f32_16x16x32_bf16(a3[1][0], c0, bs3[1], 0, 0, 0);
        f32x4 kd = __builtin_amdgcn_mfma_f32_16x16x32_bf16(a3[1][1], c1, zed, 0, 0, 0);
        k0 = ka + kb;
        k1 = kc + kd;
    };

    bf16x8 by = bounce(yD0, yD1);

    #pragma unroll 1
    for (int iv = 0; iv < NT - 1; ++iv) {
        const float hs = hsl[iv];
        #pragma unroll 1
        for (int sub = 0; sub < 2; ++sub) {
            f32x4 k1a, k1b, k2a, k2b, k3a, k3b, k4a, k4b, k5a, k5b, k6a, k6b;
            evalf(by, k1a, k1b);
            by = bounce(yD0 + hs * (0.2f * k1a),
                        yD1 + hs * (0.2f * k1b));
            evalf(by, k2a, k2b);
            by = bounce(yD0 + hs * (A31 * k1a + A32 * k2a),
                        yD1 + hs * (A31 * k1b + A32 * k2b));
            evalf(by, k3a, k3b);
            by = bounce(yD0 + hs * (A41 * k1a + A42 * k2a + A43 * k3a),
                        yD1 + hs * (A41 * k1b + A42 * k2b + A43 * k3b));
            evalf(by, k4a, k4b);
            by = bounce(yD0 + hs * (A51 * k1a + A52 * k2a + A53 * k3a + A54 * k4a),
                        yD1 + hs * (A51 * k1b + A52 * k2b + A53 * k3b + A54 * k4b));
            evalf(by, k5a, k5b);
            by = bounce(yD0 + hs * (A61 * k1a + A62 * k2a + A63 * k3a + A64 * k4a + A65 * k5a),
                        yD1 + hs * (A61 * k1b + A62 * k2b + A63 * k3b + A64 * k4b + A65 * k5b));
            evalf(by, k6a, k6b);
            yD0 = yD0 + hs * (BB1 * k1a + BB3 * k3a + BB4 * k4a + BB5 * k5a + BB6 * k6a);
            yD1 = yD1 + hs * (BB1 * k1b + BB3 * k3b + BB4 * k4b + BB5 * k5b + BB6 * k6b);
            by = bounce(yD0, yD1);
        }
        if (w == 0) {
            *(f32x4*)(out + ((size_t)(iv + 1) * NB + row0 + n) * ND + 4 * q) = yD0;
            *(f32x4*)(out + ((size_t)(iv + 1) * NB + row0 + n) * ND + 16 + 4 * q) = yD1;
        }
    }

    if (blockIdx.x == 0 && tid == 0) {
        out[(size_t)NT * NB * ND] = 62.0f;                   // num_steps = (T-1)*K
    }
}

extern "C" void kernel_launch(void* const* d_in, const int* in_sizes, int n_in,
                              void* d_out, int out_size, void* d_ws, size_t ws_size,
                              hipStream_t stream) {
    const float* ts = (const float*)d_in[0];
    const float* y0 = (const float*)d_in[1];
    const float* W1 = (const float*)d_in[2];
    const float* b1 = (const float*)d_in[3];
    const float* W2 = (const float*)d_in[4];
    const float* b2 = (const float*)d_in[5];
    const float* W3 = (const float*)d_in[6];
    const float* b3 = (const float*)d_in[7];
    float* out = (float*)d_out;

    node_kernel<<<dim3(NB / 16), dim3(256), 0, stream>>>(ts, y0, W1, b1, W2, b2, W3, b3, out);
}

// Round 6
// 261.247 us; speedup vs baseline: 1.1148x; 1.1148x over previous
//
#include <hip/hip_runtime.h>

typedef short bf16x8 __attribute__((ext_vector_type(8)));
typedef float f32x4 __attribute__((ext_vector_type(4)));
typedef unsigned int u32;

#define NT 32
#define NB 4096
#define ND 32
#define NW 64

// Dopri5 tableau
#define A31 ((float)(3.0/40.0))
#define A32 ((float)(9.0/40.0))
#define A41 ((float)(44.0/45.0))
#define A42 ((float)(-56.0/15.0))
#define A43 ((float)(32.0/9.0))
#define A51 ((float)(19372.0/6561.0))
#define A52 ((float)(-25360.0/2187.0))
#define A53 ((float)(64448.0/6561.0))
#define A54 ((float)(-212.0/729.0))
#define A61 ((float)(9017.0/3168.0))
#define A62 ((float)(-355.0/33.0))
#define A63 ((float)(46732.0/5247.0))
#define A64 ((float)(49.0/176.0))
#define A65 ((float)(-5103.0/18656.0))
#define BB1 ((float)(35.0/384.0))
#define BB3 ((float)(500.0/1113.0))
#define BB4 ((float)(125.0/192.0))
#define BB5 ((float)(-2187.0/6784.0))
#define BB6 ((float)(11.0/84.0))

// Single-instruction RNE pack: D.lo = bf16(a), D.hi = bf16(b)
__device__ __forceinline__ u32 pk(float a, float b) {
    u32 r;
    asm("v_cvt_pk_bf16_f32 %0, %1, %2" : "=v"(r) : "v"(a), "v"(b));
    return r;
}
// Direct softplus: 5 VALU (2 trans). Pre-activations here are bounded well
// below exp-overflow; negative tail loses only ~1e-9 absolute.
__device__ __forceinline__ float sp(float x) {
    return __logf(1.0f + __expf(x));
}
// Barrier that waits only on LDS (skip __syncthreads' vmcnt(0) drain of the
// outstanding global out-stores). "memory" clobber pins LDS ops on each side.
__device__ __forceinline__ void lds_barrier() {
    asm volatile("s_waitcnt lgkmcnt(0)\n\ts_barrier" ::: "memory");
}
__device__ __forceinline__ bf16x8 mk_afrag(const float* p) {
    union { u32 u[4]; bf16x8 v; } r;
    r.u[0] = pk(p[0], p[1]); r.u[1] = pk(p[2], p[3]);
    r.u[2] = pk(p[4], p[5]); r.u[3] = pk(p[6], p[7]);
    return r.v;
}

// R4 structure (best so far): 16 rows/block, 4 waves, 3 LDS barriers/eval.
// Wave w owns hidden m-tile w for L1/L2; L3 + RK state on waves 0-1 only
// (full-K MFMA -> k stays in registers). LDS tiles 16x32 u32 (128B rows),
// XOR-swizzled by ((row&7)<<2) both sides.

__global__ __launch_bounds__(256, 1)
void node_kernel(const float* __restrict__ ts, const float* __restrict__ y0,
                 const float* __restrict__ W1, const float* __restrict__ b1,
                 const float* __restrict__ W2, const float* __restrict__ b2,
                 const float* __restrict__ W3, const float* __restrict__ b3,
                 float* __restrict__ out)
{
    __shared__ __align__(16) u32 ylds[16 * 32];
    __shared__ __align__(16) u32 h1ds[16 * 32];
    __shared__ __align__(16) u32 h2ds[16 * 32];
    __shared__ float hsl[NT];

    const int tid  = threadIdx.x;
    const int w    = tid >> 6;          // wave 0..3
    const int lane = tid & 63;
    const int n    = lane & 15;         // batch col
    const int q    = lane >> 4;         // MFMA quad
    const int swz  = (n & 7) << 2;
    const int row0 = blockIdx.x * 16;

    if (tid < NT - 1) hsl[tid] = (ts[tid + 1] - ts[tid]) * 0.5f;  // K=2

    // ---- weights: wave w handles hidden m-tile w in L1/L2 ----
    bf16x8 a1   = mk_afrag(W1 + (w * 16 + n) * ND + q * 8);
    bf16x8 a2lo = mk_afrag(W2 + (w * 16 + n) * NW + q * 8);
    bf16x8 a2hi = mk_afrag(W2 + (w * 16 + n) * NW + 32 + q * 8);
    f32x4 bs1 = *(const f32x4*)(b1 + w * 16 + q * 4);
    f32x4 bs2 = *(const f32x4*)(b2 + w * 16 + q * 4);
    const f32x4 zed = {0.0f, 0.0f, 0.0f, 0.0f};

    // ---- L3 + RK state: waves 0-1 only; thread owns y[row0+n][d0..d0+3] ----
    const int d0 = w * 16 + q * 4;
    bf16x8 a3lo = {}, a3hi = {};
    f32x4 bs3 = {}, y = {};
    if (w < 2) {
        a3lo = mk_afrag(W3 + (w * 16 + n) * NW + q * 8);
        a3hi = mk_afrag(W3 + (w * 16 + n) * NW + 32 + q * 8);
        bs3 = *(const f32x4*)(b3 + w * 16 + q * 4);
        y = *(const f32x4*)(y0 + (size_t)(row0 + n) * ND + d0);
        *(f32x4*)(out + (size_t)(row0 + n) * ND + d0) = y;      // ys[0] = y0
        uint2 p; p.x = pk(y[0], y[1]); p.y = pk(y[2], y[3]);
        *(uint2*)&ylds[n * 32 + ((w * 8 + q * 2) ^ swz)] = p;
    }
    __syncthreads();   // full sync once: hsl + initial y visible

    auto writeY = [&](f32x4 vv) {      // call only on waves 0-1
        uint2 p; p.x = pk(vv[0], vv[1]); p.y = pk(vv[2], vv[3]);
        *(uint2*)&ylds[n * 32 + ((w * 8 + q * 2) ^ swz)] = p;
    };

    auto evalf = [&](f32x4& kk) {
        lds_barrier();                                       // (1) y_stage ready
        bf16x8 by = *(const bf16x8*)&ylds[n * 32 + ((q * 4) ^ swz)];
        f32x4 u = __builtin_amdgcn_mfma_f32_16x16x32_bf16(a1, by, bs1, 0, 0, 0);
        {
            uint2 p; p.x = pk(sp(u[0]), sp(u[1])); p.y = pk(sp(u[2]), sp(u[3]));
            *(uint2*)&h1ds[n * 32 + ((w * 8 + q * 2) ^ swz)] = p;
        }
        lds_barrier();                                       // (2) h1 ready
        bf16x8 bh0 = *(const bf16x8*)&h1ds[n * 32 + ((q * 4) ^ swz)];
        bf16x8 bh1 = *(const bf16x8*)&h1ds[n * 32 + ((16 + q * 4) ^ swz)];
        f32x4 va = __builtin_amdgcn_mfma_f32_16x16x32_bf16(a2lo, bh0, bs2, 0, 0, 0);
        f32x4 vb = __builtin_amdgcn_mfma_f32_16x16x32_bf16(a2hi, bh1, zed, 0, 0, 0);
        f32x4 v = va + vb;
        {
            uint2 p; p.x = pk(sp(v[0]), sp(v[1])); p.y = pk(sp(v[2]), sp(v[3]));
            *(uint2*)&h2ds[n * 32 + ((w * 8 + q * 2) ^ swz)] = p;
        }
        lds_barrier();                                       // (3) h2 ready
        if (w < 2) {
            bf16x8 c0 = *(const bf16x8*)&h2ds[n * 32 + ((q * 4) ^ swz)];
            bf16x8 c1 = *(const bf16x8*)&h2ds[n * 32 + ((16 + q * 4) ^ swz)];
            f32x4 ka = __builtin_amdgcn_mfma_f32_16x16x32_bf16(a3lo, c0, bs3, 0, 0, 0);
            f32x4 kb = __builtin_amdgcn_mfma_f32_16x16x32_bf16(a3hi, c1, zed, 0, 0, 0);
            kk = ka + kb;                                    // k in RK-state layout
        }
    };

    #pragma unroll 1
    for (int iv = 0; iv < NT - 1; ++iv) {
        const float hs = hsl[iv];
        #pragma unroll 1
        for (int sub = 0; sub < 2; ++sub) {
            f32x4 k1, k2, k3, k4, k5, k6;
            evalf(k1);
            if (w < 2) writeY(y + hs * (0.2f * k1));
            evalf(k2);
            if (w < 2) writeY(y + hs * (A31 * k1 + A32 * k2));
            evalf(k3);
            if (w < 2) writeY(y + hs * (A41 * k1 + A42 * k2 + A43 * k3));
            evalf(k4);
            if (w < 2) writeY(y + hs * (A51 * k1 + A52 * k2 + A53 * k3 + A54 * k4));
            evalf(k5);
            if (w < 2) writeY(y + hs * (A61 * k1 + A62 * k2 + A63 * k3 + A64 * k4 + A65 * k5));
            evalf(k6);
            if (w < 2) {
                y = y + hs * (BB1 * k1 + BB3 * k3 + BB4 * k4 + BB5 * k5 + BB6 * k6);
                writeY(y);
            }
        }
        if (w < 2) {
            *(f32x4*)(out + ((size_t)(iv + 1) * NB + row0 + n) * ND + d0) = y;
        }
    }

    if (blockIdx.x == 0 && tid == 0) {
        out[(size_t)NT * NB * ND] = 62.0f;                   // num_steps = (T-1)*K
    }
}

extern "C" void kernel_launch(void* const* d_in, const int* in_sizes, int n_in,
                              void* d_out, int out_size, void* d_ws, size_t ws_size,
                              hipStream_t stream) {
    const float* ts = (const float*)d_in[0];
    const float* y0 = (const float*)d_in[1];
    const float* W1 = (const float*)d_in[2];
    const float* b1 = (const float*)d_in[3];
    const float* W2 = (const float*)d_in[4];
    const float* b2 = (const float*)d_in[5];
    const float* W3 = (const float*)d_in[6];
    const float* b3 = (const float*)d_in[7];
    float* out = (float*)d_out;

    node_kernel<<<dim3(NB / 16), dim3(256), 0, stream>>>(ts, y0, W1, b1, W2, b2, W3, b3, out);
}

// Round 7
// 233.045 us; speedup vs baseline: 1.2497x; 1.1210x over previous
//
#include <hip/hip_runtime.h>

typedef short bf16x8 __attribute__((ext_vector_type(8)));
typedef float f32x4 __attribute__((ext_vector_type(4)));
typedef unsigned int u32;

#define NT 32
#define NB 4096
#define ND 32
#define NW 64

// Dopri5 tableau
#define A31 ((float)(3.0/40.0))
#define A32 ((float)(9.0/40.0))
#define A41 ((float)(44.0/45.0))
#define A42 ((float)(-56.0/15.0))
#define A43 ((float)(32.0/9.0))
#define A51 ((float)(19372.0/6561.0))
#define A52 ((float)(-25360.0/2187.0))
#define A53 ((float)(64448.0/6561.0))
#define A54 ((float)(-212.0/729.0))
#define A61 ((float)(9017.0/3168.0))
#define A62 ((float)(-355.0/33.0))
#define A63 ((float)(46732.0/5247.0))
#define A64 ((float)(49.0/176.0))
#define A65 ((float)(-5103.0/18656.0))
#define BB1 ((float)(35.0/384.0))
#define BB3 ((float)(500.0/1113.0))
#define BB4 ((float)(125.0/192.0))
#define BB5 ((float)(-2187.0/6784.0))
#define BB6 ((float)(11.0/84.0))

// Single-instruction RNE pack: D.lo = bf16(a), D.hi = bf16(b)
__device__ __forceinline__ u32 pk(float a, float b) {
    u32 r;
    asm("v_cvt_pk_bf16_f32 %0, %1, %2" : "=v"(r) : "v"(a), "v"(b));
    return r;
}
// Direct softplus: 2 trans + 2 VALU; pre-acts bounded far below overflow.
__device__ __forceinline__ float sp(float x) {
    return __logf(1.0f + __expf(x));
}
// LDS-only barrier: skip __syncthreads' vmcnt(0) drain of async out-stores.
__device__ __forceinline__ void lds_barrier() {
    asm volatile("s_waitcnt lgkmcnt(0)\n\ts_barrier" ::: "memory");
}
__device__ __forceinline__ bf16x8 mk_afrag(const float* p) {
    union { u32 u[4]; bf16x8 v; } r;
    r.u[0] = pk(p[0], p[1]); r.u[1] = pk(p[2], p[3]);
    r.u[2] = pk(p[4], p[5]); r.u[3] = pk(p[6], p[7]);
    return r.v;
}

// Structure (16 rows/block, 4 symmetric waves, 2 barriers/eval):
//  - L1/L2: wave w owns hidden m-tile w; h1/h2 exchanged via swizzled LDS.
//  - L3: PERMUTED m-tiles, computed redundantly on ALL waves:
//      tile t holds W3 rows g(t,m) = 8*(m>>2) + 4*t + (m&3),
//    so lane (q,n) accumulates exactly y-dims {8q..8q+3} (t=0) and
//    {8q+4..8q+7} (t=1) = the B-fragment k-range for the next eval's L1.
//    => RK state is register-resident in B-frag order; NO y-exchange.
//  - Math identical to reference modulo bf16 rounding (permutation only
//    reorders rows); RK combine in fp32.

__global__ __launch_bounds__(256, 1)
void node_kernel(const float* __restrict__ ts, const float* __restrict__ y0,
                 const float* __restrict__ W1, const float* __restrict__ b1,
                 const float* __restrict__ W2, const float* __restrict__ b2,
                 const float* __restrict__ W3, const float* __restrict__ b3,
                 float* __restrict__ out)
{
    __shared__ __align__(16) u32 h1ds[16 * 32];
    __shared__ __align__(16) u32 h2ds[16 * 32];
    __shared__ float hsl[NT];

    const int tid  = threadIdx.x;
    const int w    = tid >> 6;          // wave 0..3
    const int lane = tid & 63;
    const int n    = lane & 15;         // batch col / A-row slot
    const int q    = lane >> 4;         // MFMA quad
    const int swz  = (n & 7) << 2;
    const int row0 = blockIdx.x * 16;

    if (tid < NT - 1) hsl[tid] = (ts[tid + 1] - ts[tid]) * 0.5f;  // K=2

    // ---- L1/L2 weights: wave w owns hidden m-tile w ----
    bf16x8 a1   = mk_afrag(W1 + (w * 16 + n) * ND + q * 8);
    bf16x8 a2lo = mk_afrag(W2 + (w * 16 + n) * NW + q * 8);
    bf16x8 a2hi = mk_afrag(W2 + (w * 16 + n) * NW + 32 + q * 8);
    f32x4 bs1 = *(const f32x4*)(b1 + w * 16 + q * 4);
    f32x4 bs2 = *(const f32x4*)(b2 + w * 16 + q * 4);
    const f32x4 zed = {0.0f, 0.0f, 0.0f, 0.0f};

    // ---- L3 permuted A-frags, all waves: row g(t) = 8*(n>>2)+4t+(n&3) ----
    const int gb = 8 * (n >> 2) + (n & 3);
    bf16x8 a3[2][2];
    #pragma unroll
    for (int t = 0; t < 2; ++t) {
        a3[t][0] = mk_afrag(W3 + (gb + 4 * t) * NW + q * 8);
        a3[t][1] = mk_afrag(W3 + (gb + 4 * t) * NW + 32 + q * 8);
    }
    // bias in permuted D-layout: lane(q,·) reg j of tile t <- b3[8q+4t+j]
    f32x4 bs3[2];
    bs3[0] = *(const f32x4*)(b3 + 8 * q);
    bs3[1] = *(const f32x4*)(b3 + 8 * q + 4);

    // ---- RK state: lane (q,n) owns y[row0+n][8q..8q+7] (B-frag order) ----
    f32x4 yA = *(const f32x4*)(y0 + (size_t)(row0 + n) * ND + 8 * q);
    f32x4 yB = *(const f32x4*)(y0 + (size_t)(row0 + n) * ND + 8 * q + 4);
    if (w == 0) {
        *(f32x4*)(out + (size_t)(row0 + n) * ND + 8 * q)     = yA;  // ys[0]
        *(f32x4*)(out + (size_t)(row0 + n) * ND + 8 * q + 4) = yB;
    }
    __syncthreads();    // hsl visible

    // stage-y (fp32 x8, this lane's dims) -> bf16 B-fragment, pure registers
    auto mkby = [&](f32x4 sA, f32x4 sB) -> bf16x8 {
        union { u32 u[4]; bf16x8 v; } r;
        r.u[0] = pk(sA[0], sA[1]); r.u[1] = pk(sA[2], sA[3]);
        r.u[2] = pk(sB[0], sB[1]); r.u[3] = pk(sB[2], sB[3]);
        return r.v;
    };

    auto evalf = [&](bf16x8 by, f32x4& kA, f32x4& kB) {
        // L1 (wave's m-tile)
        f32x4 u = __builtin_amdgcn_mfma_f32_16x16x32_bf16(a1, by, bs1, 0, 0, 0);
        {
            uint2 p; p.x = pk(sp(u[0]), sp(u[1])); p.y = pk(sp(u[2]), sp(u[3]));
            *(uint2*)&h1ds[n * 32 + ((w * 8 + q * 2) ^ swz)] = p;
        }
        lds_barrier();                                       // B1: h1 ready
        bf16x8 bh0 = *(const bf16x8*)&h1ds[n * 32 + ((q * 4) ^ swz)];
        bf16x8 bh1 = *(const bf16x8*)&h1ds[n * 32 + ((16 + q * 4) ^ swz)];
        f32x4 va = __builtin_amdgcn_mfma_f32_16x16x32_bf16(a2lo, bh0, bs2, 0, 0, 0);
        f32x4 vb = __builtin_amdgcn_mfma_f32_16x16x32_bf16(a2hi, bh1, zed, 0, 0, 0);
        f32x4 v = va + vb;
        {
            uint2 p; p.x = pk(sp(v[0]), sp(v[1])); p.y = pk(sp(v[2]), sp(v[3]));
            *(uint2*)&h2ds[n * 32 + ((w * 8 + q * 2) ^ swz)] = p;
        }
        lds_barrier();                                       // B2: h2 ready
        bf16x8 c0 = *(const bf16x8*)&h2ds[n * 32 + ((q * 4) ^ swz)];
        bf16x8 c1 = *(const bf16x8*)&h2ds[n * 32 + ((16 + q * 4) ^ swz)];
        // L3 on all waves, permuted tiles; two independent C-chains
        f32x4 tA = __builtin_amdgcn_mfma_f32_16x16x32_bf16(a3[0][0], c0, bs3[0], 0, 0, 0);
        f32x4 tB = __builtin_amdgcn_mfma_f32_16x16x32_bf16(a3[1][0], c0, bs3[1], 0, 0, 0);
        kA = __builtin_amdgcn_mfma_f32_16x16x32_bf16(a3[0][1], c1, tA, 0, 0, 0);
        kB = __builtin_amdgcn_mfma_f32_16x16x32_bf16(a3[1][1], c1, tB, 0, 0, 0);
    };

    bf16x8 by = mkby(yA, yB);

    #pragma unroll 1
    for (int iv = 0; iv < NT - 1; ++iv) {
        const float hs = hsl[iv];
        #pragma unroll 1
        for (int sub = 0; sub < 2; ++sub) {
            f32x4 k1A, k1B, k2A, k2B, k3A, k3B, k4A, k4B, k5A, k5B, k6A, k6B;
            evalf(by, k1A, k1B);
            by = mkby(yA + hs * (0.2f * k1A),
                      yB + hs * (0.2f * k1B));
            evalf(by, k2A, k2B);
            by = mkby(yA + hs * (A31 * k1A + A32 * k2A),
                      yB + hs * (A31 * k1B + A32 * k2B));
            evalf(by, k3A, k3B);
            by = mkby(yA + hs * (A41 * k1A + A42 * k2A + A43 * k3A),
                      yB + hs * (A41 * k1B + A42 * k2B + A43 * k3B));
            evalf(by, k4A, k4B);
            by = mkby(yA + hs * (A51 * k1A + A52 * k2A + A53 * k3A + A54 * k4A),
                      yB + hs * (A51 * k1B + A52 * k2B + A53 * k3B + A54 * k4B));
            evalf(by, k5A, k5B);
            by = mkby(yA + hs * (A61 * k1A + A62 * k2A + A63 * k3A + A64 * k4A + A65 * k5A),
                      yB + hs * (A61 * k1B + A62 * k2B + A63 * k3B + A64 * k4B + A65 * k5B));
            evalf(by, k6A, k6B);
            yA = yA + hs * (BB1 * k1A + BB3 * k3A + BB4 * k4A + BB5 * k5A + BB6 * k6A);
            yB = yB + hs * (BB1 * k1B + BB3 * k3B + BB4 * k4B + BB5 * k5B + BB6 * k6B);
            by = mkby(yA, yB);
        }
        if (w == 0) {
            *(f32x4*)(out + ((size_t)(iv + 1) * NB + row0 + n) * ND + 8 * q)     = yA;
            *(f32x4*)(out + ((size_t)(iv + 1) * NB + row0 + n) * ND + 8 * q + 4) = yB;
        }
    }

    if (blockIdx.x == 0 && tid == 0) {
        out[(size_t)NT * NB * ND] = 62.0f;                   // num_steps = (T-1)*K
    }
}

extern "C" void kernel_launch(void* const* d_in, const int* in_sizes, int n_in,
                              void* d_out, int out_size, void* d_ws, size_t ws_size,
                              hipStream_t stream) {
    const float* ts = (const float*)d_in[0];
    const float* y0 = (const float*)d_in[1];
    const float* W1 = (const float*)d_in[2];
    const float* b1 = (const float*)d_in[3];
    const float* W2 = (const float*)d_in[4];
    const float* b2 = (const float*)d_in[5];
    const float* W3 = (const float*)d_in[6];
    const float* b3 = (const float*)d_in[7];
    float* out = (float*)d_out;

    node_kernel<<<dim3(NB / 16), dim3(256), 0, stream>>>(ts, y0, W1, b1, W2, b2, W3, b3, out);
}